// Round 1
// baseline (713.314 us; speedup 1.0000x reference)
//
#include <hip/hip_runtime.h>
#include <hip/hip_bf16.h>

#define DIM  256
#define NSEQ 8192
#define BATCH 8
#define WIN  512

typedef __attribute__((ext_vector_type(8))) short short8;   // bf16x8 MFMA frag (4 VGPRs)
typedef __attribute__((ext_vector_type(4))) float floatx4;  // MFMA acc

union PFU { int i[4]; short8 v; };

__device__ __forceinline__ int packbf(float a, float b) {
    __hip_bfloat162 h;
    h.x = __float2bfloat16(a);
    h.y = __float2bfloat16(b);
    int r;
    __builtin_memcpy(&r, &h, 4);
    return r;
}

__device__ __forceinline__ void gld_lds16(void* lds_dst, const void* g_src) {
    __builtin_amdgcn_global_load_lds(
        (const __attribute__((address_space(1))) void*)g_src,
        (__attribute__((address_space(3))) void*)lds_dst,
        16, 0, 0);
}

// ---------------------------------------------------------------------------
// Kernel 1: x (B, D, N) f32  ->  xT (B, N, D) bf16
// ---------------------------------------------------------------------------
__global__ __launch_bounds__(256) void k_transpose(const float* __restrict__ x,
                                                   __hip_bfloat16* __restrict__ xT) {
    __shared__ float tile[64][65];
    const int b  = blockIdx.z;
    const int n0 = blockIdx.x * 64;
    const int d0 = blockIdx.y * 64;
    const int t  = threadIdx.x;
    const int ln = t & 63, grp = t >> 6;

    const float* xb = x + (size_t)b * DIM * NSEQ;
#pragma unroll
    for (int i = 0; i < 16; ++i) {
        int d = grp * 16 + i;
        tile[d][ln] = xb[(size_t)(d0 + d) * NSEQ + n0 + ln];
    }
    __syncthreads();
    __hip_bfloat16* xTb = xT + (size_t)b * NSEQ * DIM;
#pragma unroll
    for (int i = 0; i < 16; ++i) {
        int n = grp * 16 + i;
        xTb[(size_t)(n0 + n) * DIM + d0 + ln] = __float2bfloat16(tile[ln][n]);
    }
}

// ---------------------------------------------------------------------------
// Kernel 2: Wq,Wk,Wv f32 -> packed bf16 buffer wb[3][256*256]
// ---------------------------------------------------------------------------
__global__ __launch_bounds__(256) void k_wcast(const float* __restrict__ w0,
                                               const float* __restrict__ w1,
                                               const float* __restrict__ w2,
                                               __hip_bfloat16* __restrict__ wb) {
    int i = (blockIdx.x * 256 + threadIdx.x) * 4;   // 0..196604
    const float* s = (i < 65536) ? (w0 + i) : ((i < 131072) ? (w1 + i - 65536) : (w2 + i - 131072));
    float4 v = *(const float4*)s;
    union { __hip_bfloat16 h[4]; ushort4 u; } cv;
    cv.h[0] = __float2bfloat16(v.x);
    cv.h[1] = __float2bfloat16(v.y);
    cv.h[2] = __float2bfloat16(v.z);
    cv.h[3] = __float2bfloat16(v.w);
    *(ushort4*)(wb + i) = cv.u;
}

// ---------------------------------------------------------------------------
// Kernel 3: projection GEMMs (m97 structure, 128x128 tile, BK=32)
//   mode 0: Q[n][i] = xT[n][:]·Wq[i][:] + bq[i]      (A=xT, B=Wq)
//   mode 1: K[n][i] = ... Wk ...                      (A=xT, B=Wk)
//   mode 2: Vt[i][n] = Wv[i][:]·xT[n][:] + bv[i]      (A=Wv, B=xT)  -> transposed V for free
// ---------------------------------------------------------------------------
__global__ __launch_bounds__(256) void k_proj(const __hip_bfloat16* __restrict__ xT,
                                              const __hip_bfloat16* __restrict__ wb,
                                              const float* __restrict__ bq,
                                              const float* __restrict__ bk,
                                              const float* __restrict__ bv,
                                              __hip_bfloat16* __restrict__ qo,
                                              __hip_bfloat16* __restrict__ ko,
                                              __hip_bfloat16* __restrict__ vto) {
    __shared__ __hip_bfloat16 As[4096];   // 128 rows x 32 k (bf16) = 8 KB
    __shared__ __hip_bfloat16 Bs[4096];

    const int mode = blockIdx.y;
    const int b    = blockIdx.z;
    const int xb   = blockIdx.x;
    const int tid  = threadIdx.x;
    const int wv   = tid >> 6;
    const int l    = tid & 63;
    const int qd   = l >> 4;
    const int lm   = l & 15;
    const int wm   = (wv & 1) * 64;
    const int wn   = (wv >> 1) * 64;

    int m0, n0;
    const __hip_bfloat16 *Ap, *Bp;
    const __hip_bfloat16* xTb = xT + (size_t)b * NSEQ * DIM;
    if (mode < 2) {
        m0 = (xb >> 1) * 128;  n0 = (xb & 1) * 128;
        Ap = xTb + (size_t)m0 * DIM;
        Bp = wb + mode * 65536 + (size_t)n0 * DIM;
    } else {
        m0 = (xb & 1) * 128;   n0 = (xb >> 1) * 128;
        Ap = wb + 2 * 65536 + (size_t)m0 * DIM;
        Bp = xTb + (size_t)n0 * DIM;
    }

    floatx4 acc[4][4];
#pragma unroll
    for (int i = 0; i < 4; ++i)
#pragma unroll
        for (int j = 0; j < 4; ++j) acc[i][j] = (floatx4){0.f, 0.f, 0.f, 0.f};

    for (int k0 = 0; k0 < DIM; k0 += 32) {
#pragma unroll
        for (int r = 0; r < 2; ++r) {
            int row = r * 64 + (tid >> 2);
            int seg = (tid & 3) * 8;
            gld_lds16((char*)As + r * 4096 + wv * 1024, Ap + (size_t)row * DIM + k0 + seg);
            gld_lds16((char*)Bs + r * 4096 + wv * 1024, Bp + (size_t)row * DIM + k0 + seg);
        }
        __syncthreads();
        short8 af[4], bfv[4];
#pragma unroll
        for (int mt = 0; mt < 4; ++mt)
            af[mt] = *(const short8*)(As + (wm + mt * 16 + lm) * 32 + qd * 8);
#pragma unroll
        for (int nt = 0; nt < 4; ++nt)
            bfv[nt] = *(const short8*)(Bs + (wn + nt * 16 + lm) * 32 + qd * 8);
#pragma unroll
        for (int mt = 0; mt < 4; ++mt)
#pragma unroll
            for (int nt = 0; nt < 4; ++nt)
                acc[mt][nt] = __builtin_amdgcn_mfma_f32_16x16x32_bf16(af[mt], bfv[nt], acc[mt][nt], 0, 0, 0);
        __syncthreads();
    }

    const float* bias = (mode == 0) ? bq : ((mode == 1) ? bk : bv);
    __hip_bfloat16* op;
    size_t ostr;
    if (mode == 0)      { op = qo  + (size_t)b * NSEQ * DIM; ostr = DIM; }
    else if (mode == 1) { op = ko  + (size_t)b * NSEQ * DIM; ostr = DIM; }
    else                { op = vto + (size_t)b * DIM * NSEQ; ostr = NSEQ; }

    float bc[4];
    if (mode < 2) {
#pragma unroll
        for (int nt = 0; nt < 4; ++nt) bc[nt] = bias[n0 + wn + nt * 16 + lm];
    }
#pragma unroll
    for (int mt = 0; mt < 4; ++mt)
#pragma unroll
        for (int nt = 0; nt < 4; ++nt)
#pragma unroll
            for (int r = 0; r < 4; ++r) {
                int row = wm + mt * 16 + qd * 4 + r;
                int col = wn + nt * 16 + lm;
                float bb = (mode < 2) ? bc[nt] : bias[m0 + row];
                op[(size_t)(m0 + row) * ostr + n0 + col] = __float2bfloat16(acc[mt][nt][r] + bb);
            }
}

// ---------------------------------------------------------------------------
// Kernel 4: sliding-window flash attention + residual + transpose-back.
// Per wave: 16 q-rows. Computes S^T = K·Q^T and O^T = V^T·P^T so that the
// softmax row index == lane&15 for S, stats, P and O (all lane-local), and
// the output write out[b][d][n] is 16-lane coalesced in n.
// ---------------------------------------------------------------------------
__global__ __launch_bounds__(256, 2) void k_attn(const __hip_bfloat16* __restrict__ qm,
                                                 const __hip_bfloat16* __restrict__ km,
                                                 const __hip_bfloat16* __restrict__ vtm,
                                                 const float* __restrict__ x,
                                                 float* __restrict__ out) {
    const int b  = blockIdx.z, w = blockIdx.y, qt = blockIdx.x;
    const int tid = threadIdx.x;
    const int wv = tid >> 6;
    const int l  = tid & 63;
    const int m  = l & 15;   // q-row within the wave's 16
    const int qd = l >> 4;   // quad

    const int qb    = qt * 64 + wv * 16;       // q base within window [0,512)
    const int koff0 = w * WIN - WIN;           // global row of key_local 0

    const __hip_bfloat16* qrow = qm + ((size_t)b * NSEQ + (size_t)(w * WIN + qb + m)) * DIM;
    short8 qf[8];
#pragma unroll
    for (int s = 0; s < 8; ++s)
        qf[s] = *(const short8*)(qrow + s * 32 + qd * 8);

    const __hip_bfloat16* kbase = km + (size_t)b * NSEQ * DIM;
    const __hip_bfloat16* vbase = vtm + (size_t)b * DIM * NSEQ;

    floatx4 o[16];
#pragma unroll
    for (int t = 0; t < 16; ++t) o[t] = (floatx4){0.f, 0.f, 0.f, 0.f};

    float mi = -INFINITY, li = 0.f;
    const int lim = 512 + qb + m;              // last valid key_local for row m
    const int c0  = (w == 0) ? 8 : 0;          // skip nonexistent previous window
    const int c1  = (512 + qb + 16 + 63) >> 6; // exclusive chunk end
    const float sscale = 0.0625f * 1.4426950408889634f;  // D^-0.5 * log2(e)

    const int a0 = (((qd & 1) * 2) * 16 + m) * 4;  // bpermute byte addrs
    const int a1 = a0 + 64;
    const bool hi = (qd >> 1) != 0;

    for (int c = c0; c < c1; ++c) {
        const int kv0 = c * 64;
        // ---- S^T = K · Q^T ----
        floatx4 st[4];
#pragma unroll
        for (int t = 0; t < 4; ++t) {
            const __hip_bfloat16* kr = kbase + (size_t)(koff0 + kv0 + t * 16 + m) * DIM + qd * 8;
            short8 kf[8];
#pragma unroll
            for (int s = 0; s < 8; ++s) kf[s] = *(const short8*)(kr + s * 32);
            floatx4 a = (floatx4){0.f, 0.f, 0.f, 0.f};
#pragma unroll
            for (int s = 0; s < 8; ++s)
                a = __builtin_amdgcn_mfma_f32_16x16x32_bf16(kf[s], qf[s], a, 0, 0, 0);
            st[t] = a;
        }
        // ---- scale + causal mask ----
        const bool needmask = (kv0 + 63) > (512 + qb);
        float p[16];
#pragma unroll
        for (int t = 0; t < 4; ++t)
#pragma unroll
            for (int r = 0; r < 4; ++r) {
                float v = st[t][r] * sscale;
                if (needmask) {
                    int key = kv0 + t * 16 + qd * 4 + r;
                    v = (key <= lim) ? v : -INFINITY;
                }
                p[t * 4 + r] = v;
            }
        // ---- online softmax (row == lane&15; reduce across quads) ----
        float mx = p[0];
#pragma unroll
        for (int i = 1; i < 16; ++i) mx = fmaxf(mx, p[i]);
        mx = fmaxf(mx, __shfl_xor(mx, 16, 64));
        mx = fmaxf(mx, __shfl_xor(mx, 32, 64));
        const float mnew  = fmaxf(mi, mx);
        const float alpha = exp2f(mi - mnew);
        float ps = 0.f;
#pragma unroll
        for (int i = 0; i < 16; ++i) { p[i] = exp2f(p[i] - mnew); ps += p[i]; }
        ps += __shfl_xor(ps, 16, 64);
        ps += __shfl_xor(ps, 32, 64);
        li = li * alpha + ps;
        mi = mnew;
#pragma unroll
        for (int t = 0; t < 16; ++t) {
            o[t][0] *= alpha; o[t][1] *= alpha; o[t][2] *= alpha; o[t][3] *= alpha;
        }
        // ---- pack P^T to bf16 and quad-shuffle into A/B fragment layout ----
        int pd[8];
#pragma unroll
        for (int t = 0; t < 4; ++t) {
            pd[t * 2 + 0] = packbf(p[t * 4 + 0], p[t * 4 + 1]);
            pd[t * 2 + 1] = packbf(p[t * 4 + 2], p[t * 4 + 3]);
        }
        short8 pf[2];
#pragma unroll
        for (int s = 0; s < 2; ++s) {
            int x0 = __builtin_amdgcn_ds_bpermute(a0, pd[(2 * s) * 2 + 0]);
            int y0 = __builtin_amdgcn_ds_bpermute(a0, pd[(2 * s + 1) * 2 + 0]);
            int x1 = __builtin_amdgcn_ds_bpermute(a0, pd[(2 * s) * 2 + 1]);
            int y1 = __builtin_amdgcn_ds_bpermute(a0, pd[(2 * s + 1) * 2 + 1]);
            int x2 = __builtin_amdgcn_ds_bpermute(a1, pd[(2 * s) * 2 + 0]);
            int y2 = __builtin_amdgcn_ds_bpermute(a1, pd[(2 * s + 1) * 2 + 0]);
            int x3 = __builtin_amdgcn_ds_bpermute(a1, pd[(2 * s) * 2 + 1]);
            int y3 = __builtin_amdgcn_ds_bpermute(a1, pd[(2 * s + 1) * 2 + 1]);
            PFU u;
            u.i[0] = hi ? y0 : x0;
            u.i[1] = hi ? y1 : x1;
            u.i[2] = hi ? y2 : x2;
            u.i[3] = hi ? y3 : x3;
            pf[s] = u.v;
        }
        // ---- O^T += V^T · P^T ----
#pragma unroll
        for (int t = 0; t < 16; ++t) {
            const __hip_bfloat16* vr = vbase + (size_t)(t * 16 + m) * NSEQ + (koff0 + kv0) + qd * 8;
            short8 v0 = *(const short8*)(vr);
            short8 v1 = *(const short8*)(vr + 32);
            o[t] = __builtin_amdgcn_mfma_f32_16x16x32_bf16(v0, pf[0], o[t], 0, 0, 0);
            o[t] = __builtin_amdgcn_mfma_f32_16x16x32_bf16(v1, pf[1], o[t], 0, 0, 0);
        }
    }
    // ---- epilogue: O/l + residual, write out[b][d][n] (coalesced in n) ----
    const float inv = 1.f / li;
    const int ng = w * WIN + qb + m;
    const float* xr  = x   + (size_t)b * DIM * NSEQ + ng;
    float*       orw = out + (size_t)b * DIM * NSEQ + ng;
#pragma unroll
    for (int t = 0; t < 16; ++t)
#pragma unroll
        for (int r = 0; r < 4; ++r) {
            int d = t * 16 + qd * 4 + r;
            orw[(size_t)d * NSEQ] = xr[(size_t)d * NSEQ] + o[t][r] * inv;
        }
}

// ---------------------------------------------------------------------------
extern "C" void kernel_launch(void* const* d_in, const int* in_sizes, int n_in,
                              void* d_out, int out_size, void* d_ws, size_t ws_size,
                              hipStream_t stream) {
    const float* x  = (const float*)d_in[0];
    const float* Wq = (const float*)d_in[1];
    const float* bq = (const float*)d_in[2];
    const float* Wk = (const float*)d_in[3];
    const float* bk = (const float*)d_in[4];
    const float* Wv = (const float*)d_in[5];
    const float* bv = (const float*)d_in[6];

    char* ws = (char*)d_ws;
    const size_t SZ = (size_t)BATCH * NSEQ * DIM * sizeof(__hip_bfloat16);  // 32 MB
    __hip_bfloat16* xT  = (__hip_bfloat16*)(ws);
    __hip_bfloat16* qb_ = (__hip_bfloat16*)(ws + SZ);
    __hip_bfloat16* kb_ = (__hip_bfloat16*)(ws + 2 * SZ);
    __hip_bfloat16* vt_ = (__hip_bfloat16*)(ws + 3 * SZ);
    __hip_bfloat16* wb_ = (__hip_bfloat16*)(ws + 4 * SZ);                   // 384 KB

    k_transpose<<<dim3(NSEQ / 64, DIM / 64, BATCH), 256, 0, stream>>>(x, xT);
    k_wcast<<<dim3(192), 256, 0, stream>>>(Wq, Wk, Wv, wb_);
    k_proj<<<dim3(128, 3, BATCH), 256, 0, stream>>>(xT, wb_, bq, bk, bv, qb_, kb_, vt_);
    k_attn<<<dim3(8, 16, BATCH), 256, 0, stream>>>(qb_, kb_, vt_, x, (float*)d_out);
}

// Round 3
// 582.616 us; speedup vs baseline: 1.2243x; 1.2243x over previous
//
#include <hip/hip_runtime.h>
#include <hip/hip_bf16.h>

#define DIM  256
#define NSEQ 8192
#define BATCH 8
#define WIN  512

typedef __attribute__((ext_vector_type(8))) short short8;   // bf16x8 MFMA frag (4 VGPRs)
typedef __attribute__((ext_vector_type(4))) float floatx4;  // MFMA acc

union PFU { int i[4]; short8 v; };

__device__ __forceinline__ int packbf(float a, float b) {
    __hip_bfloat162 h;
    h.x = __float2bfloat16(a);
    h.y = __float2bfloat16(b);
    int r;
    __builtin_memcpy(&r, &h, 4);
    return r;
}

__device__ __forceinline__ void gld_lds16(void* lds_dst, const void* g_src) {
    __builtin_amdgcn_global_load_lds(
        (const __attribute__((address_space(1))) void*)g_src,
        (__attribute__((address_space(3))) void*)lds_dst,
        16, 0, 0);
}

// ---------------------------------------------------------------------------
// Kernel 1: x (B, D, N) f32  ->  xT (B, N, D) bf16
// ---------------------------------------------------------------------------
__global__ __launch_bounds__(256) void k_transpose(const float* __restrict__ x,
                                                   __hip_bfloat16* __restrict__ xT) {
    __shared__ float tile[64][65];
    const int b  = blockIdx.z;
    const int n0 = blockIdx.x * 64;
    const int d0 = blockIdx.y * 64;
    const int t  = threadIdx.x;
    const int ln = t & 63, grp = t >> 6;

    const float* xb = x + (size_t)b * DIM * NSEQ;
#pragma unroll
    for (int i = 0; i < 16; ++i) {
        int d = grp * 16 + i;
        tile[d][ln] = xb[(size_t)(d0 + d) * NSEQ + n0 + ln];
    }
    __syncthreads();
    __hip_bfloat16* xTb = xT + (size_t)b * NSEQ * DIM;
#pragma unroll
    for (int i = 0; i < 16; ++i) {
        int n = grp * 16 + i;
        xTb[(size_t)(n0 + n) * DIM + d0 + ln] = __float2bfloat16(tile[ln][n]);
    }
}

// ---------------------------------------------------------------------------
// Kernel 2: Wq,Wk,Wv f32 -> packed bf16 buffer wb[3][256*256]
// ---------------------------------------------------------------------------
__global__ __launch_bounds__(256) void k_wcast(const float* __restrict__ w0,
                                               const float* __restrict__ w1,
                                               const float* __restrict__ w2,
                                               __hip_bfloat16* __restrict__ wb) {
    int i = (blockIdx.x * 256 + threadIdx.x) * 4;
    const float* s = (i < 65536) ? (w0 + i) : ((i < 131072) ? (w1 + i - 65536) : (w2 + i - 131072));
    float4 v = *(const float4*)s;
    union { __hip_bfloat16 h[4]; ushort4 u; } cv;
    cv.h[0] = __float2bfloat16(v.x);
    cv.h[1] = __float2bfloat16(v.y);
    cv.h[2] = __float2bfloat16(v.z);
    cv.h[3] = __float2bfloat16(v.w);
    *(ushort4*)(wb + i) = cv.u;
}

// ---------------------------------------------------------------------------
// Kernel 3: projection GEMMs (m97 structure, 128x128 tile, BK=32)
// ---------------------------------------------------------------------------
__global__ __launch_bounds__(256) void k_proj(const __hip_bfloat16* __restrict__ xT,
                                              const __hip_bfloat16* __restrict__ wb,
                                              const float* __restrict__ bq,
                                              const float* __restrict__ bk,
                                              const float* __restrict__ bv,
                                              __hip_bfloat16* __restrict__ qo,
                                              __hip_bfloat16* __restrict__ ko,
                                              __hip_bfloat16* __restrict__ vto) {
    __shared__ __hip_bfloat16 As[4096];
    __shared__ __hip_bfloat16 Bs[4096];

    const int mode = blockIdx.y;
    const int b    = blockIdx.z;
    const int xb   = blockIdx.x;
    const int tid  = threadIdx.x;
    const int wv   = tid >> 6;
    const int l    = tid & 63;
    const int qd   = l >> 4;
    const int lm   = l & 15;
    const int wm   = (wv & 1) * 64;
    const int wn   = (wv >> 1) * 64;

    int m0, n0;
    const __hip_bfloat16 *Ap, *Bp;
    const __hip_bfloat16* xTb = xT + (size_t)b * NSEQ * DIM;
    if (mode < 2) {
        m0 = (xb >> 1) * 128;  n0 = (xb & 1) * 128;
        Ap = xTb + (size_t)m0 * DIM;
        Bp = wb + mode * 65536 + (size_t)n0 * DIM;
    } else {
        m0 = (xb & 1) * 128;   n0 = (xb >> 1) * 128;
        Ap = wb + 2 * 65536 + (size_t)m0 * DIM;
        Bp = xTb + (size_t)n0 * DIM;
    }

    floatx4 acc[4][4];
#pragma unroll
    for (int i = 0; i < 4; ++i)
#pragma unroll
        for (int j = 0; j < 4; ++j) acc[i][j] = (floatx4){0.f, 0.f, 0.f, 0.f};

    for (int k0 = 0; k0 < DIM; k0 += 32) {
#pragma unroll
        for (int r = 0; r < 2; ++r) {
            int row = r * 64 + (tid >> 2);
            int seg = (tid & 3) * 8;
            gld_lds16((char*)As + r * 4096 + wv * 1024, Ap + (size_t)row * DIM + k0 + seg);
            gld_lds16((char*)Bs + r * 4096 + wv * 1024, Bp + (size_t)row * DIM + k0 + seg);
        }
        __syncthreads();
        short8 af[4], bfv[4];
#pragma unroll
        for (int mt = 0; mt < 4; ++mt)
            af[mt] = *(const short8*)(As + (wm + mt * 16 + lm) * 32 + qd * 8);
#pragma unroll
        for (int nt = 0; nt < 4; ++nt)
            bfv[nt] = *(const short8*)(Bs + (wn + nt * 16 + lm) * 32 + qd * 8);
#pragma unroll
        for (int mt = 0; mt < 4; ++mt)
#pragma unroll
            for (int nt = 0; nt < 4; ++nt)
                acc[mt][nt] = __builtin_amdgcn_mfma_f32_16x16x32_bf16(af[mt], bfv[nt], acc[mt][nt], 0, 0, 0);
        __syncthreads();
    }

    const float* bias = (mode == 0) ? bq : ((mode == 1) ? bk : bv);
    __hip_bfloat16* op;
    size_t ostr;
    if (mode == 0)      { op = qo  + (size_t)b * NSEQ * DIM; ostr = DIM; }
    else if (mode == 1) { op = ko  + (size_t)b * NSEQ * DIM; ostr = DIM; }
    else                { op = vto + (size_t)b * DIM * NSEQ; ostr = NSEQ; }

    float bc[4];
    if (mode < 2) {
#pragma unroll
        for (int nt = 0; nt < 4; ++nt) bc[nt] = bias[n0 + wn + nt * 16 + lm];
    }
#pragma unroll
    for (int mt = 0; mt < 4; ++mt)
#pragma unroll
        for (int nt = 0; nt < 4; ++nt)
#pragma unroll
            for (int r = 0; r < 4; ++r) {
                int row = wm + mt * 16 + qd * 4 + r;
                int col = wn + nt * 16 + lm;
                float bb = (mode < 2) ? bc[nt] : bias[m0 + row];
                op[(size_t)(m0 + row) * ostr + n0 + col] = __float2bfloat16(acc[mt][nt][r] + bb);
            }
}

// ---------------------------------------------------------------------------
// Kernel 4: sliding-window flash attention, LDS-shared K/V chunks.
// Staging mechanism: per-lane global_load -> VGPR -> ds_write_b128 (explicit,
// fully-architectural scatter; replaces the R1 global_load_lds DMA). Single
// barrier per chunk: iter c does ds_write(chunk c+1, regs loaded last iter),
// issues global loads for chunk c+2, computes chunk c from buf[pb], barrier.
// The ds_write's vmcnt wait covers loads issued one full compute-phase ago.
// LDS layout: slot jj (K: jj=t*8+s, V: jj=t) at jj*1024 + lane*16 holds the
// exact 16B fragment lane reads with ds_read_b128 (stride-1, conflict-free).
// ---------------------------------------------------------------------------
__global__ __launch_bounds__(256, 2) void k_attn(const __hip_bfloat16* __restrict__ qm,
                                                 const __hip_bfloat16* __restrict__ km,
                                                 const __hip_bfloat16* __restrict__ vtm,
                                                 const float* __restrict__ x,
                                                 float* __restrict__ out) {
    __shared__ __align__(16) char kbuf[2][16384];
    __shared__ __align__(16) char vbuf[2][16384];

    const int b  = blockIdx.z, w = blockIdx.y, qt = blockIdx.x;
    const int tid = threadIdx.x;
    const int wv = tid >> 6;
    const int l  = tid & 63;
    const int m  = l & 15;   // q-row (and fragment row) within 16
    const int qd = l >> 4;   // quad

    const int qb    = qt * 64 + wv * 16;   // q base within window [0,512)
    const int koff0 = w * WIN - WIN;       // global row of key_local 0

    // ---- Q fragments (private, once) ----
    const __hip_bfloat16* qrow = qm + ((size_t)b * NSEQ + (size_t)(w * WIN + qb + m)) * DIM;
    short8 qf[8];
#pragma unroll
    for (int s = 0; s < 8; ++s)
        qf[s] = *(const short8*)(qrow + s * 32 + qd * 8);

    const char* kbase = (const char*)(km + (size_t)b * NSEQ * DIM);
    const char* vbase = (const char*)(vtm + (size_t)b * DIM * NSEQ);

    const int c0  = (w == 0) ? 16 : 0;                  // skip nonexistent prev window
    const int c1w = (512 + qb + 47) >> 5;               // per-wave exclusive chunk end
    const int c1b = (512 + qt * 64 + 48 + 47) >> 5;     // block-level end (top wave)

    // ---- staging: waves 0,1 own K slots jj=wv*8+i; waves 2,3 own V slots t=(wv-2)*8+i ----
    const bool   isK     = wv < 2;
    const size_t gstride = isK ? (size_t)64 : (size_t)16 * NSEQ * 2;   // i-step
    const size_t adv     = isK ? (size_t)32 * 512 : (size_t)64;        // chunk-step
    const int    lbase   = (isK ? wv * 8 : (wv - 2) * 8) * 1024 + l * 16;
    const char* gp0;
    if (isK)
        gp0 = kbase + (size_t)(koff0 + c0 * 32 + wv * 16 + m) * 512 + (size_t)qd * 16;
    else
        gp0 = vbase + (size_t)((wv - 2) * 128 + m) * (NSEQ * 2) +
              (size_t)(koff0 + c0 * 32) * 2 + (size_t)qd * 16;

    // ---- prologue: load chunk c0, write to buf[0], load chunk c0+1 ----
    int4 rg[8];
#pragma unroll
    for (int i = 0; i < 8; ++i)
        rg[i] = *(const int4*)(gp0 + (size_t)i * gstride);
    gp0 += adv;
    {
        char* d0 = (isK ? kbuf[0] : vbuf[0]) + lbase;
#pragma unroll
        for (int i = 0; i < 8; ++i)
            *(int4*)(d0 + i * 1024) = rg[i];
    }
    if (c0 + 1 < c1b) {
#pragma unroll
        for (int i = 0; i < 8; ++i)
            rg[i] = *(const int4*)(gp0 + (size_t)i * gstride);
        gp0 += adv;
    }

    floatx4 o[16];
#pragma unroll
    for (int t = 0; t < 16; ++t) o[t] = (floatx4){0.f, 0.f, 0.f, 0.f};
    float mi = -INFINITY, li = 0.f;
    const int lim = 512 + qb + m;
    const float sscale = 0.0625f * 1.4426950408889634f;  // D^-0.5 * log2(e)

    const int a0 = (((qd & 1) * 2) * 16 + m) * 4;  // bpermute byte addrs
    const int a1 = a0 + 64;
    const bool hi = (qd >> 1) != 0;

    __syncthreads();  // buf[0] ready
    int pb = 0;
    for (int c = c0; c < c1b; ++c) {
        // ---- stage chunk c+1 (regs -> buf[pb^1]); vmcnt wait hits loads from last iter ----
        if (c + 1 < c1b) {
            char* dst = (isK ? kbuf[pb ^ 1] : vbuf[pb ^ 1]) + lbase;
#pragma unroll
            for (int i = 0; i < 8; ++i)
                *(int4*)(dst + i * 1024) = rg[i];
        }
        // ---- issue loads for chunk c+2 ----
        if (c + 2 < c1b) {
#pragma unroll
            for (int i = 0; i < 8; ++i)
                rg[i] = *(const int4*)(gp0 + (size_t)i * gstride);
            gp0 += adv;
        }
        // ---- compute chunk c from buf[pb] ----
        if (c < c1w) {
            const char* kbp = kbuf[pb];
            floatx4 st[2];
#pragma unroll
            for (int t = 0; t < 2; ++t) {
                floatx4 a = (floatx4){0.f, 0.f, 0.f, 0.f};
#pragma unroll
                for (int s = 0; s < 8; ++s) {
                    short8 kf = *(const short8*)(kbp + ((t * 8 + s) * 64 + l) * 16);
                    a = __builtin_amdgcn_mfma_f32_16x16x32_bf16(kf, qf[s], a, 0, 0, 0);
                }
                st[t] = a;
            }
            const int kl0 = c * 32;
            const bool needmask = (kl0 + 31) > lim;
            float p[8];
#pragma unroll
            for (int t = 0; t < 2; ++t)
#pragma unroll
                for (int r = 0; r < 4; ++r) {
                    float v = st[t][r] * sscale;
                    if (needmask) {
                        int key = kl0 + t * 16 + qd * 4 + r;
                        v = (key <= lim) ? v : -INFINITY;
                    }
                    p[t * 4 + r] = v;
                }
            float mx = p[0];
#pragma unroll
            for (int i = 1; i < 8; ++i) mx = fmaxf(mx, p[i]);
            mx = fmaxf(mx, __shfl_xor(mx, 16, 64));
            mx = fmaxf(mx, __shfl_xor(mx, 32, 64));
            const float mnew  = fmaxf(mi, mx);
            const float alpha = exp2f(mi - mnew);
            float ps = 0.f;
#pragma unroll
            for (int i = 0; i < 8; ++i) { p[i] = exp2f(p[i] - mnew); ps += p[i]; }
            ps += __shfl_xor(ps, 16, 64);
            ps += __shfl_xor(ps, 32, 64);
            li = li * alpha + ps;
            mi = mnew;
#pragma unroll
            for (int t = 0; t < 16; ++t) {
                o[t][0] *= alpha; o[t][1] *= alpha; o[t][2] *= alpha; o[t][3] *= alpha;
            }
            // ---- pack P^T (bf16) + quad shuffle into B-fragment layout ----
            int pd0 = packbf(p[0], p[1]);
            int pd1 = packbf(p[2], p[3]);
            int pd2 = packbf(p[4], p[5]);
            int pd3 = packbf(p[6], p[7]);
            int x0 = __builtin_amdgcn_ds_bpermute(a0, pd0);
            int y0 = __builtin_amdgcn_ds_bpermute(a0, pd2);
            int x1 = __builtin_amdgcn_ds_bpermute(a0, pd1);
            int y1 = __builtin_amdgcn_ds_bpermute(a0, pd3);
            int x2 = __builtin_amdgcn_ds_bpermute(a1, pd0);
            int y2 = __builtin_amdgcn_ds_bpermute(a1, pd2);
            int x3 = __builtin_amdgcn_ds_bpermute(a1, pd1);
            int y3 = __builtin_amdgcn_ds_bpermute(a1, pd3);
            PFU u;
            u.i[0] = hi ? y0 : x0;
            u.i[1] = hi ? y1 : x1;
            u.i[2] = hi ? y2 : x2;
            u.i[3] = hi ? y3 : x3;
            short8 pf = u.v;
            // ---- O^T += V^T · P^T ----
            const char* vbp = vbuf[pb];
#pragma unroll
            for (int t = 0; t < 16; ++t) {
                short8 vf = *(const short8*)(vbp + (t * 64 + l) * 16);
                o[t] = __builtin_amdgcn_mfma_f32_16x16x32_bf16(vf, pf, o[t], 0, 0, 0);
            }
        }
        __syncthreads();  // buf[pb^1] ready for next iter; readers of buf[pb] done
        pb ^= 1;
    }

    // ---- epilogue: O/l + residual, write out[b][d][n] (coalesced in n) ----
    const float inv = 1.f / li;
    const int ng = w * WIN + qb + m;
    const float* xr  = x   + (size_t)b * DIM * NSEQ + ng;
    float*       orw = out + (size_t)b * DIM * NSEQ + ng;
#pragma unroll
    for (int t = 0; t < 16; ++t)
#pragma unroll
        for (int r = 0; r < 4; ++r) {
            int d = t * 16 + qd * 4 + r;
            orw[(size_t)d * NSEQ] = xr[(size_t)d * NSEQ] + o[t][r] * inv;
        }
}

// ---------------------------------------------------------------------------
extern "C" void kernel_launch(void* const* d_in, const int* in_sizes, int n_in,
                              void* d_out, int out_size, void* d_ws, size_t ws_size,
                              hipStream_t stream) {
    const float* x  = (const float*)d_in[0];
    const float* Wq = (const float*)d_in[1];
    const float* bq = (const float*)d_in[2];
    const float* Wk = (const float*)d_in[3];
    const float* bk = (const float*)d_in[4];
    const float* Wv = (const float*)d_in[5];
    const float* bv = (const float*)d_in[6];

    char* ws = (char*)d_ws;
    const size_t SZ = (size_t)BATCH * NSEQ * DIM * sizeof(__hip_bfloat16);  // 32 MB
    __hip_bfloat16* xT  = (__hip_bfloat16*)(ws);
    __hip_bfloat16* qb_ = (__hip_bfloat16*)(ws + SZ);
    __hip_bfloat16* kb_ = (__hip_bfloat16*)(ws + 2 * SZ);
    __hip_bfloat16* vt_ = (__hip_bfloat16*)(ws + 3 * SZ);
    __hip_bfloat16* wb_ = (__hip_bfloat16*)(ws + 4 * SZ);                   // 384 KB

    k_transpose<<<dim3(NSEQ / 64, DIM / 64, BATCH), 256, 0, stream>>>(x, xT);
    k_wcast<<<dim3(192), 256, 0, stream>>>(Wq, Wk, Wv, wb_);
    k_proj<<<dim3(128, 3, BATCH), 256, 0, stream>>>(xT, wb_, bq, bk, bv, qb_, kb_, vt_);
    k_attn<<<dim3(8, 16, BATCH), 256, 0, stream>>>(qb_, kb_, vt_, x, (float*)d_out);
}

// Round 4
// 372.357 us; speedup vs baseline: 1.9157x; 1.5647x over previous
//
#include <hip/hip_runtime.h>
#include <hip/hip_bf16.h>

#define DIM  256
#define NSEQ 8192
#define BATCH 8
#define WIN  512

typedef __attribute__((ext_vector_type(8))) short short8;   // bf16x8 MFMA frag (4 VGPRs)
typedef __attribute__((ext_vector_type(4))) float floatx4;  // MFMA acc

union PFU { int i[4]; short8 v; };

__device__ __forceinline__ int packbf(float a, float b) {
    __hip_bfloat162 h;
    h.x = __float2bfloat16(a);
    h.y = __float2bfloat16(b);
    int r;
    __builtin_memcpy(&r, &h, 4);
    return r;
}

__device__ __forceinline__ void gld_lds16(void* lds_dst, const void* g_src) {
    __builtin_amdgcn_global_load_lds(
        (const __attribute__((address_space(1))) void*)g_src,
        (__attribute__((address_space(3))) void*)lds_dst,
        16, 0, 0);
}

// ---------------------------------------------------------------------------
// Kernel 1: x (B, D, N) f32  ->  xT (B, N, D) bf16
// ---------------------------------------------------------------------------
__global__ __launch_bounds__(256) void k_transpose(const float* __restrict__ x,
                                                   __hip_bfloat16* __restrict__ xT) {
    __shared__ float tile[64][65];
    const int b  = blockIdx.z;
    const int n0 = blockIdx.x * 64;
    const int d0 = blockIdx.y * 64;
    const int t  = threadIdx.x;
    const int ln = t & 63, grp = t >> 6;

    const float* xb = x + (size_t)b * DIM * NSEQ;
#pragma unroll
    for (int i = 0; i < 16; ++i) {
        int d = grp * 16 + i;
        tile[d][ln] = xb[(size_t)(d0 + d) * NSEQ + n0 + ln];
    }
    __syncthreads();
    __hip_bfloat16* xTb = xT + (size_t)b * NSEQ * DIM;
#pragma unroll
    for (int i = 0; i < 16; ++i) {
        int n = grp * 16 + i;
        xTb[(size_t)(n0 + n) * DIM + d0 + ln] = __float2bfloat16(tile[ln][n]);
    }
}

// ---------------------------------------------------------------------------
// Kernel 2: Wq,Wk,Wv f32 -> packed bf16 buffer wb[3][256*256]
// ---------------------------------------------------------------------------
__global__ __launch_bounds__(256) void k_wcast(const float* __restrict__ w0,
                                               const float* __restrict__ w1,
                                               const float* __restrict__ w2,
                                               __hip_bfloat16* __restrict__ wb) {
    int i = (blockIdx.x * 256 + threadIdx.x) * 4;
    const float* s = (i < 65536) ? (w0 + i) : ((i < 131072) ? (w1 + i - 65536) : (w2 + i - 131072));
    float4 v = *(const float4*)s;
    union { __hip_bfloat16 h[4]; ushort4 u; } cv;
    cv.h[0] = __float2bfloat16(v.x);
    cv.h[1] = __float2bfloat16(v.y);
    cv.h[2] = __float2bfloat16(v.z);
    cv.h[3] = __float2bfloat16(v.w);
    *(ushort4*)(wb + i) = cv.u;
}

// ---------------------------------------------------------------------------
// Kernel 3: projection GEMMs (m97 structure, 128x128 tile, BK=32)
// ---------------------------------------------------------------------------
__global__ __launch_bounds__(256) void k_proj(const __hip_bfloat16* __restrict__ xT,
                                              const __hip_bfloat16* __restrict__ wb,
                                              const float* __restrict__ bq,
                                              const float* __restrict__ bk,
                                              const float* __restrict__ bv,
                                              __hip_bfloat16* __restrict__ qo,
                                              __hip_bfloat16* __restrict__ ko,
                                              __hip_bfloat16* __restrict__ vto) {
    __shared__ __hip_bfloat16 As[4096];
    __shared__ __hip_bfloat16 Bs[4096];

    const int mode = blockIdx.y;
    const int b    = blockIdx.z;
    const int xb   = blockIdx.x;
    const int tid  = threadIdx.x;
    const int wv   = tid >> 6;
    const int l    = tid & 63;
    const int qd   = l >> 4;
    const int lm   = l & 15;
    const int wm   = (wv & 1) * 64;
    const int wn   = (wv >> 1) * 64;

    int m0, n0;
    const __hip_bfloat16 *Ap, *Bp;
    const __hip_bfloat16* xTb = xT + (size_t)b * NSEQ * DIM;
    if (mode < 2) {
        m0 = (xb >> 1) * 128;  n0 = (xb & 1) * 128;
        Ap = xTb + (size_t)m0 * DIM;
        Bp = wb + mode * 65536 + (size_t)n0 * DIM;
    } else {
        m0 = (xb & 1) * 128;   n0 = (xb >> 1) * 128;
        Ap = wb + 2 * 65536 + (size_t)m0 * DIM;
        Bp = xTb + (size_t)n0 * DIM;
    }

    floatx4 acc[4][4];
#pragma unroll
    for (int i = 0; i < 4; ++i)
#pragma unroll
        for (int j = 0; j < 4; ++j) acc[i][j] = (floatx4){0.f, 0.f, 0.f, 0.f};

    for (int k0 = 0; k0 < DIM; k0 += 32) {
#pragma unroll
        for (int r = 0; r < 2; ++r) {
            int row = r * 64 + (tid >> 2);
            int seg = (tid & 3) * 8;
            gld_lds16((char*)As + r * 4096 + wv * 1024, Ap + (size_t)row * DIM + k0 + seg);
            gld_lds16((char*)Bs + r * 4096 + wv * 1024, Bp + (size_t)row * DIM + k0 + seg);
        }
        __syncthreads();
        short8 af[4], bfv[4];
#pragma unroll
        for (int mt = 0; mt < 4; ++mt)
            af[mt] = *(const short8*)(As + (wm + mt * 16 + lm) * 32 + qd * 8);
#pragma unroll
        for (int nt = 0; nt < 4; ++nt)
            bfv[nt] = *(const short8*)(Bs + (wn + nt * 16 + lm) * 32 + qd * 8);
#pragma unroll
        for (int mt = 0; mt < 4; ++mt)
#pragma unroll
            for (int nt = 0; nt < 4; ++nt)
                acc[mt][nt] = __builtin_amdgcn_mfma_f32_16x16x32_bf16(af[mt], bfv[nt], acc[mt][nt], 0, 0, 0);
        __syncthreads();
    }

    const float* bias = (mode == 0) ? bq : ((mode == 1) ? bk : bv);
    __hip_bfloat16* op;
    size_t ostr;
    if (mode == 0)      { op = qo  + (size_t)b * NSEQ * DIM; ostr = DIM; }
    else if (mode == 1) { op = ko  + (size_t)b * NSEQ * DIM; ostr = DIM; }
    else                { op = vto + (size_t)b * DIM * NSEQ; ostr = NSEQ; }

    float bc[4];
    if (mode < 2) {
#pragma unroll
        for (int nt = 0; nt < 4; ++nt) bc[nt] = bias[n0 + wn + nt * 16 + lm];
    }
#pragma unroll
    for (int mt = 0; mt < 4; ++mt)
#pragma unroll
        for (int nt = 0; nt < 4; ++nt)
#pragma unroll
            for (int r = 0; r < 4; ++r) {
                int row = wm + mt * 16 + qd * 4 + r;
                int col = wn + nt * 16 + lm;
                float bb = (mode < 2) ? bc[nt] : bias[m0 + row];
                op[(size_t)(m0 + row) * ostr + n0 + col] = __float2bfloat16(acc[mt][nt][r] + bb);
            }
}

// ---------------------------------------------------------------------------
// Kernel 4: sliding-window flash attention.
// R4 changes vs R3:
//  * 512-thread blocks: 8 waves x 16 q = 128 q per block -> K/V chunks shared
//    by 2x more q (staging issue halved); staging regs shrink to rg[4].
//  * Staging registers never cross a barrier: iter c does
//      load rg(c+1) -> compute(c) -> ds_write rg -> barrier
//    (kills the R3 cross-barrier live range that forced scratch spills = the
//    700 MB phantom WRITE_SIZE).
//  * Grid (w, b, qt): sibling qt blocks differ by 128 in linear id == same XCD
//    (id%8), so their shared K/V window lives in one L2.
// LDS layout unchanged: slot jj at jj*1024 + lane*16 holds the exact 16B unit
// lane ds_read_b128s for its fragment (stride-1, conflict-free).
// Staging roles: waves 0-3 own K slots jj=wv*4+i (t=wv>>1, s=(wv&1)*4+i);
// waves 4-7 own V slots t=(wv-4)*4+i.
// ---------------------------------------------------------------------------
__global__ __launch_bounds__(512, 2) void k_attn(const __hip_bfloat16* __restrict__ qm,
                                                 const __hip_bfloat16* __restrict__ km,
                                                 const __hip_bfloat16* __restrict__ vtm,
                                                 const float* __restrict__ x,
                                                 float* __restrict__ out) {
    __shared__ __align__(16) char kbuf[2][16384];
    __shared__ __align__(16) char vbuf[2][16384];

    const int w  = blockIdx.x, b = blockIdx.y, qt = blockIdx.z;
    const int tid = threadIdx.x;
    const int wv = tid >> 6;
    const int l  = tid & 63;
    const int m  = l & 15;   // q-row (and fragment row) within 16
    const int qd = l >> 4;   // quad

    const int qb    = qt * 128 + wv * 16;  // q base within window [0,512)
    const int koff0 = w * WIN - WIN;       // global row of key_local 0

    // ---- Q fragments (private, once) ----
    const __hip_bfloat16* qrow = qm + ((size_t)b * NSEQ + (size_t)(w * WIN + qb + m)) * DIM;
    short8 qf[8];
#pragma unroll
    for (int s = 0; s < 8; ++s)
        qf[s] = *(const short8*)(qrow + s * 32 + qd * 8);

    const char* kbase = (const char*)(km + (size_t)b * NSEQ * DIM);
    const char* vbase = (const char*)(vtm + (size_t)b * DIM * NSEQ);

    const int c0  = (w == 0) ? 16 : 0;                  // skip nonexistent prev window
    const int c1w = (512 + qb + 47) >> 5;               // per-wave exclusive chunk end
    const int c1b = (671 + qt * 128) >> 5;              // block-level end (top wave)

    // ---- staging role ----
    const bool   isK     = wv < 4;
    const size_t gstride = isK ? (size_t)64 : (size_t)16 * NSEQ * 2;   // i-step
    const size_t adv     = isK ? (size_t)32 * 512 : (size_t)64;        // chunk-step
    const int    lbase   = (isK ? wv * 4 : (wv - 4) * 4) * 1024 + l * 16;
    const char* gp0;
    if (isK)
        gp0 = kbase + (size_t)(koff0 + c0 * 32 + (wv >> 1) * 16 + m) * 512 +
              (size_t)((wv & 1) * 16 + qd) * 16;
    else
        gp0 = vbase + (size_t)((wv - 4) * 64 + m) * (NSEQ * 2) +
              (size_t)(koff0 + c0 * 32) * 2 + (size_t)qd * 16;

    floatx4 o[16];
#pragma unroll
    for (int t = 0; t < 16; ++t) o[t] = (floatx4){0.f, 0.f, 0.f, 0.f};
    float mi = -INFINITY, li = 0.f;
    const int lim = 512 + qb + m;
    const float sscale = 0.0625f * 1.4426950408889634f;  // D^-0.5 * log2(e)

    const int a0 = (((qd & 1) * 2) * 16 + m) * 4;  // bpermute byte addrs
    const int a1 = a0 + 64;
    const bool hi = (qd >> 1) != 0;

    // ---- prologue: stage chunk c0 into buf[0] ----
    int4 rg[4];
#pragma unroll
    for (int i = 0; i < 4; ++i)
        rg[i] = *(const int4*)(gp0 + (size_t)i * gstride);
    gp0 += adv;
    {
        char* d0 = (isK ? kbuf[0] : vbuf[0]) + lbase;
#pragma unroll
        for (int i = 0; i < 4; ++i)
            *(int4*)(d0 + i * 1024) = rg[i];
    }
    __syncthreads();  // buf[0] ready

    int pb = 0;
    for (int c = c0; c < c1b; ++c) {
        const bool more = (c + 1 < c1b);
        // ---- issue loads for chunk c+1 (in flight during compute) ----
        if (more) {
#pragma unroll
            for (int i = 0; i < 4; ++i)
                rg[i] = *(const int4*)(gp0 + (size_t)i * gstride);
            gp0 += adv;
        }
        // ---- compute chunk c from buf[pb] ----
        if (c < c1w) {
            const char* kbp = kbuf[pb];
            floatx4 st[2];
#pragma unroll
            for (int t = 0; t < 2; ++t) {
                floatx4 a = (floatx4){0.f, 0.f, 0.f, 0.f};
#pragma unroll
                for (int s = 0; s < 8; ++s) {
                    short8 kf = *(const short8*)(kbp + ((t * 8 + s) * 64 + l) * 16);
                    a = __builtin_amdgcn_mfma_f32_16x16x32_bf16(kf, qf[s], a, 0, 0, 0);
                }
                st[t] = a;
            }
            const int kl0 = c * 32;
            const bool needmask = (kl0 + 31) > lim;
            float p[8];
#pragma unroll
            for (int t = 0; t < 2; ++t)
#pragma unroll
                for (int r = 0; r < 4; ++r) {
                    float v = st[t][r] * sscale;
                    if (needmask) {
                        int key = kl0 + t * 16 + qd * 4 + r;
                        v = (key <= lim) ? v : -INFINITY;
                    }
                    p[t * 4 + r] = v;
                }
            float mx = p[0];
#pragma unroll
            for (int i = 1; i < 8; ++i) mx = fmaxf(mx, p[i]);
            mx = fmaxf(mx, __shfl_xor(mx, 16, 64));
            mx = fmaxf(mx, __shfl_xor(mx, 32, 64));
            const float mnew  = fmaxf(mi, mx);
            const float alpha = exp2f(mi - mnew);
            float ps = 0.f;
#pragma unroll
            for (int i = 0; i < 8; ++i) { p[i] = exp2f(p[i] - mnew); ps += p[i]; }
            ps += __shfl_xor(ps, 16, 64);
            ps += __shfl_xor(ps, 32, 64);
            li = li * alpha + ps;
            mi = mnew;
#pragma unroll
            for (int t = 0; t < 16; ++t) {
                o[t][0] *= alpha; o[t][1] *= alpha; o[t][2] *= alpha; o[t][3] *= alpha;
            }
            // ---- pack P^T (bf16) + quad shuffle into B-fragment layout ----
            int pd0 = packbf(p[0], p[1]);
            int pd1 = packbf(p[2], p[3]);
            int pd2 = packbf(p[4], p[5]);
            int pd3 = packbf(p[6], p[7]);
            int x0 = __builtin_amdgcn_ds_bpermute(a0, pd0);
            int y0 = __builtin_amdgcn_ds_bpermute(a0, pd2);
            int x1 = __builtin_amdgcn_ds_bpermute(a0, pd1);
            int y1 = __builtin_amdgcn_ds_bpermute(a0, pd3);
            int x2 = __builtin_amdgcn_ds_bpermute(a1, pd0);
            int y2 = __builtin_amdgcn_ds_bpermute(a1, pd2);
            int x3 = __builtin_amdgcn_ds_bpermute(a1, pd1);
            int y3 = __builtin_amdgcn_ds_bpermute(a1, pd3);
            PFU u;
            u.i[0] = hi ? y0 : x0;
            u.i[1] = hi ? y1 : x1;
            u.i[2] = hi ? y2 : x2;
            u.i[3] = hi ? y3 : x3;
            short8 pf = u.v;
            // ---- O^T += V^T · P^T ----
            const char* vbp = vbuf[pb];
#pragma unroll
            for (int t = 0; t < 16; ++t) {
                short8 vf = *(const short8*)(vbp + (t * 64 + l) * 16);
                o[t] = __builtin_amdgcn_mfma_f32_16x16x32_bf16(vf, pf, o[t], 0, 0, 0);
            }
        }
        // ---- stage chunk c+1 (regs -> buf[pb^1]); rg dies here, same iter ----
        if (more) {
            char* dst = (isK ? kbuf[pb ^ 1] : vbuf[pb ^ 1]) + lbase;
#pragma unroll
            for (int i = 0; i < 4; ++i)
                *(int4*)(dst + i * 1024) = rg[i];
        }
        __syncthreads();
        pb ^= 1;
    }

    // ---- epilogue: O/l + residual, write out[b][d][n] (coalesced in n) ----
    const float inv = 1.f / li;
    const int ng = w * WIN + qb + m;
    const float* xr  = x   + (size_t)b * DIM * NSEQ + ng;
    float*       orw = out + (size_t)b * DIM * NSEQ + ng;
#pragma unroll
    for (int t = 0; t < 16; ++t)
#pragma unroll
        for (int r = 0; r < 4; ++r) {
            int d = t * 16 + qd * 4 + r;
            orw[(size_t)d * NSEQ] = xr[(size_t)d * NSEQ] + o[t][r] * inv;
        }
}

// ---------------------------------------------------------------------------
extern "C" void kernel_launch(void* const* d_in, const int* in_sizes, int n_in,
                              void* d_out, int out_size, void* d_ws, size_t ws_size,
                              hipStream_t stream) {
    const float* x  = (const float*)d_in[0];
    const float* Wq = (const float*)d_in[1];
    const float* bq = (const float*)d_in[2];
    const float* Wk = (const float*)d_in[3];
    const float* bk = (const float*)d_in[4];
    const float* Wv = (const float*)d_in[5];
    const float* bv = (const float*)d_in[6];

    char* ws = (char*)d_ws;
    const size_t SZ = (size_t)BATCH * NSEQ * DIM * sizeof(__hip_bfloat16);  // 32 MB
    __hip_bfloat16* xT  = (__hip_bfloat16*)(ws);
    __hip_bfloat16* qb_ = (__hip_bfloat16*)(ws + SZ);
    __hip_bfloat16* kb_ = (__hip_bfloat16*)(ws + 2 * SZ);
    __hip_bfloat16* vt_ = (__hip_bfloat16*)(ws + 3 * SZ);
    __hip_bfloat16* wb_ = (__hip_bfloat16*)(ws + 4 * SZ);                   // 384 KB

    k_transpose<<<dim3(NSEQ / 64, DIM / 64, BATCH), 256, 0, stream>>>(x, xT);
    k_wcast<<<dim3(192), 256, 0, stream>>>(Wq, Wk, Wv, wb_);
    k_proj<<<dim3(128, 3, BATCH), 256, 0, stream>>>(xT, wb_, bq, bk, bv, qb_, kb_, vt_);
    k_attn<<<dim3(16, BATCH, 4), 512, 0, stream>>>(qb_, kb_, vt_, x, (float*)d_out);
}

// Round 5
// 354.085 us; speedup vs baseline: 2.0145x; 1.0516x over previous
//
#include <hip/hip_runtime.h>
#include <hip/hip_bf16.h>

#define DIM  256
#define NSEQ 8192
#define BATCH 8
#define WIN  512

typedef __attribute__((ext_vector_type(8))) short short8;   // bf16x8 MFMA frag (4 VGPRs)
typedef __attribute__((ext_vector_type(4))) float floatx4;  // MFMA acc

union PFU { int i[4]; short8 v; };

__device__ __forceinline__ int packbf(float a, float b) {
    __hip_bfloat162 h;
    h.x = __float2bfloat16(a);
    h.y = __float2bfloat16(b);
    int r;
    __builtin_memcpy(&r, &h, 4);
    return r;
}

__device__ __forceinline__ void gld_lds16(void* lds_dst, const void* g_src) {
    __builtin_amdgcn_global_load_lds(
        (const __attribute__((address_space(1))) void*)g_src,
        (__attribute__((address_space(3))) void*)lds_dst,
        16, 0, 0);
}

// ---------------------------------------------------------------------------
// Kernel 1: x (B, D, N) f32  ->  xT (B, N, D) bf16
// ---------------------------------------------------------------------------
__global__ __launch_bounds__(256) void k_transpose(const float* __restrict__ x,
                                                   __hip_bfloat16* __restrict__ xT) {
    __shared__ float tile[64][65];
    const int b  = blockIdx.z;
    const int n0 = blockIdx.x * 64;
    const int d0 = blockIdx.y * 64;
    const int t  = threadIdx.x;
    const int ln = t & 63, grp = t >> 6;

    const float* xb = x + (size_t)b * DIM * NSEQ;
#pragma unroll
    for (int i = 0; i < 16; ++i) {
        int d = grp * 16 + i;
        tile[d][ln] = xb[(size_t)(d0 + d) * NSEQ + n0 + ln];
    }
    __syncthreads();
    __hip_bfloat16* xTb = xT + (size_t)b * NSEQ * DIM;
#pragma unroll
    for (int i = 0; i < 16; ++i) {
        int n = grp * 16 + i;
        xTb[(size_t)(n0 + n) * DIM + d0 + ln] = __float2bfloat16(tile[ln][n]);
    }
}

// ---------------------------------------------------------------------------
// Kernel 2: Wq,Wk,Wv f32 -> packed bf16 buffer wb[3][256*256]
// ---------------------------------------------------------------------------
__global__ __launch_bounds__(256) void k_wcast(const float* __restrict__ w0,
                                               const float* __restrict__ w1,
                                               const float* __restrict__ w2,
                                               __hip_bfloat16* __restrict__ wb) {
    int i = (blockIdx.x * 256 + threadIdx.x) * 4;
    const float* s = (i < 65536) ? (w0 + i) : ((i < 131072) ? (w1 + i - 65536) : (w2 + i - 131072));
    float4 v = *(const float4*)s;
    union { __hip_bfloat16 h[4]; ushort4 u; } cv;
    cv.h[0] = __float2bfloat16(v.x);
    cv.h[1] = __float2bfloat16(v.y);
    cv.h[2] = __float2bfloat16(v.z);
    cv.h[3] = __float2bfloat16(v.w);
    *(ushort4*)(wb + i) = cv.u;
}

// ---------------------------------------------------------------------------
// Kernel 3: projection GEMMs (m97 structure, 128x128 tile, BK=32)
// ---------------------------------------------------------------------------
__global__ __launch_bounds__(256) void k_proj(const __hip_bfloat16* __restrict__ xT,
                                              const __hip_bfloat16* __restrict__ wb,
                                              const float* __restrict__ bq,
                                              const float* __restrict__ bk,
                                              const float* __restrict__ bv,
                                              __hip_bfloat16* __restrict__ qo,
                                              __hip_bfloat16* __restrict__ ko,
                                              __hip_bfloat16* __restrict__ vto) {
    __shared__ __hip_bfloat16 As[4096];
    __shared__ __hip_bfloat16 Bs[4096];

    const int mode = blockIdx.y;
    const int b    = blockIdx.z;
    const int xb   = blockIdx.x;
    const int tid  = threadIdx.x;
    const int wv   = tid >> 6;
    const int l    = tid & 63;
    const int qd   = l >> 4;
    const int lm   = l & 15;
    const int wm   = (wv & 1) * 64;
    const int wn   = (wv >> 1) * 64;

    int m0, n0;
    const __hip_bfloat16 *Ap, *Bp;
    const __hip_bfloat16* xTb = xT + (size_t)b * NSEQ * DIM;
    if (mode < 2) {
        m0 = (xb >> 1) * 128;  n0 = (xb & 1) * 128;
        Ap = xTb + (size_t)m0 * DIM;
        Bp = wb + mode * 65536 + (size_t)n0 * DIM;
    } else {
        m0 = (xb & 1) * 128;   n0 = (xb >> 1) * 128;
        Ap = wb + 2 * 65536 + (size_t)m0 * DIM;
        Bp = xTb + (size_t)n0 * DIM;
    }

    floatx4 acc[4][4];
#pragma unroll
    for (int i = 0; i < 4; ++i)
#pragma unroll
        for (int j = 0; j < 4; ++j) acc[i][j] = (floatx4){0.f, 0.f, 0.f, 0.f};

    for (int k0 = 0; k0 < DIM; k0 += 32) {
#pragma unroll
        for (int r = 0; r < 2; ++r) {
            int row = r * 64 + (tid >> 2);
            int seg = (tid & 3) * 8;
            gld_lds16((char*)As + r * 4096 + wv * 1024, Ap + (size_t)row * DIM + k0 + seg);
            gld_lds16((char*)Bs + r * 4096 + wv * 1024, Bp + (size_t)row * DIM + k0 + seg);
        }
        __syncthreads();
        short8 af[4], bfv[4];
#pragma unroll
        for (int mt = 0; mt < 4; ++mt)
            af[mt] = *(const short8*)(As + (wm + mt * 16 + lm) * 32 + qd * 8);
#pragma unroll
        for (int nt = 0; nt < 4; ++nt)
            bfv[nt] = *(const short8*)(Bs + (wn + nt * 16 + lm) * 32 + qd * 8);
#pragma unroll
        for (int mt = 0; mt < 4; ++mt)
#pragma unroll
            for (int nt = 0; nt < 4; ++nt)
                acc[mt][nt] = __builtin_amdgcn_mfma_f32_16x16x32_bf16(af[mt], bfv[nt], acc[mt][nt], 0, 0, 0);
        __syncthreads();
    }

    const float* bias = (mode == 0) ? bq : ((mode == 1) ? bk : bv);
    __hip_bfloat16* op;
    size_t ostr;
    if (mode == 0)      { op = qo  + (size_t)b * NSEQ * DIM; ostr = DIM; }
    else if (mode == 1) { op = ko  + (size_t)b * NSEQ * DIM; ostr = DIM; }
    else                { op = vto + (size_t)b * DIM * NSEQ; ostr = NSEQ; }

    float bc[4];
    if (mode < 2) {
#pragma unroll
        for (int nt = 0; nt < 4; ++nt) bc[nt] = bias[n0 + wn + nt * 16 + lm];
    }
#pragma unroll
    for (int mt = 0; mt < 4; ++mt)
#pragma unroll
        for (int nt = 0; nt < 4; ++nt)
#pragma unroll
            for (int r = 0; r < 4; ++r) {
                int row = wm + mt * 16 + qd * 4 + r;
                int col = wn + nt * 16 + lm;
                float bb = (mode < 2) ? bc[nt] : bias[m0 + row];
                op[(size_t)(m0 + row) * ostr + n0 + col] = __float2bfloat16(acc[mt][nt][r] + bb);
            }
}

// ---------------------------------------------------------------------------
// Kernel 4: sliding-window flash attention with register-level frag reuse.
// R5 vs R4: each wave owns 32 q (2 q-tiles). Every K/V fragment read from LDS
// feeds TWO MFMAs (one per q-tile) -> LDS read traffic per unit work halves
// (the R4 bottleneck: 1:1 MFMA:ds_read_b128 demanded ~512 B/cyc of A-operand
// vs 128 B/cyc LDS supply). Block = 8 waves = 256 q; grid (w, b, qt2) = 256
// blocks = 1/CU. Staging identical to R4 (regs never cross barriers; waves
// 0-3 stage K slots wv*4+i, waves 4-7 stage V slots (wv-4)*4+i).
// ---------------------------------------------------------------------------
__global__ __launch_bounds__(512, 2) void k_attn(const __hip_bfloat16* __restrict__ qm,
                                                 const __hip_bfloat16* __restrict__ km,
                                                 const __hip_bfloat16* __restrict__ vtm,
                                                 const float* __restrict__ x,
                                                 float* __restrict__ out) {
    __shared__ __align__(16) char kbuf[2][16384];
    __shared__ __align__(16) char vbuf[2][16384];

    const int w  = blockIdx.x, b = blockIdx.y, qt = blockIdx.z;
    const int tid = threadIdx.x;
    const int wv = tid >> 6;
    const int l  = tid & 63;
    const int m  = l & 15;   // q-row (and fragment row) within 16
    const int qd = l >> 4;   // quad

    const int qbw   = qt * 256 + wv * 32;  // wave q-base within window [0,512)
    const int koff0 = w * WIN - WIN;       // global row of key_local 0

    // ---- Q fragments for both q-tiles (private, once) ----
    short8 qf[2][8];
#pragma unroll
    for (int u = 0; u < 2; ++u) {
        const __hip_bfloat16* qrow =
            qm + ((size_t)b * NSEQ + (size_t)(w * WIN + qbw + u * 16 + m)) * DIM;
#pragma unroll
        for (int s = 0; s < 8; ++s)
            qf[u][s] = *(const short8*)(qrow + s * 32 + qd * 8);
    }

    const char* kbase = (const char*)(km + (size_t)b * NSEQ * DIM);
    const char* vbase = (const char*)(vtm + (size_t)b * DIM * NSEQ);

    const int c0  = (w == 0) ? 16 : 0;               // skip nonexistent prev window
    const int c1w = (512 + qbw + 63) >> 5;           // per-wave exclusive chunk end
    const int c1b = (799 + qt * 256) >> 5;           // block-level end (top wave)

    // ---- staging role (identical layout to R4) ----
    const bool   isK     = wv < 4;
    const size_t gstride = isK ? (size_t)64 : (size_t)16 * NSEQ * 2;   // i-step
    const size_t adv     = isK ? (size_t)32 * 512 : (size_t)64;        // chunk-step
    const int    lbase   = (isK ? wv * 4 : (wv - 4) * 4) * 1024 + l * 16;
    const char* gp0;
    if (isK)
        gp0 = kbase + (size_t)(koff0 + c0 * 32 + (wv >> 1) * 16 + m) * 512 +
              (size_t)((wv & 1) * 16 + qd) * 16;
    else
        gp0 = vbase + (size_t)((wv - 4) * 64 + m) * (NSEQ * 2) +
              (size_t)(koff0 + c0 * 32) * 2 + (size_t)qd * 16;

    floatx4 o[2][16];
#pragma unroll
    for (int u = 0; u < 2; ++u)
#pragma unroll
        for (int t = 0; t < 16; ++t) o[u][t] = (floatx4){0.f, 0.f, 0.f, 0.f};
    float mi[2] = {-INFINITY, -INFINITY};
    float li[2] = {0.f, 0.f};
    const float sscale = 0.0625f * 1.4426950408889634f;  // D^-0.5 * log2(e)

    const int a0 = (((qd & 1) * 2) * 16 + m) * 4;  // bpermute byte addrs
    const int a1 = a0 + 64;
    const bool hi = (qd >> 1) != 0;

    // ---- prologue: stage chunk c0 into buf[0] ----
    int4 rg[4];
#pragma unroll
    for (int i = 0; i < 4; ++i)
        rg[i] = *(const int4*)(gp0 + (size_t)i * gstride);
    gp0 += adv;
    {
        char* d0 = (isK ? kbuf[0] : vbuf[0]) + lbase;
#pragma unroll
        for (int i = 0; i < 4; ++i)
            *(int4*)(d0 + i * 1024) = rg[i];
    }
    __syncthreads();  // buf[0] ready

    int pb = 0;
    for (int c = c0; c < c1b; ++c) {
        const bool more = (c + 1 < c1b);
        // ---- issue loads for chunk c+1 (in flight during compute) ----
        if (more) {
#pragma unroll
            for (int i = 0; i < 4; ++i)
                rg[i] = *(const int4*)(gp0 + (size_t)i * gstride);
            gp0 += adv;
        }
        // ---- compute chunk c from buf[pb] ----
        if (c < c1w) {
            const char* kbp = kbuf[pb];
            // S^T = K · Q^T, both q-tiles per kf read (2x reuse)
            floatx4 st[2][2];
#pragma unroll
            for (int u = 0; u < 2; ++u)
#pragma unroll
                for (int t = 0; t < 2; ++t) st[u][t] = (floatx4){0.f, 0.f, 0.f, 0.f};
#pragma unroll
            for (int t = 0; t < 2; ++t)
#pragma unroll
                for (int s = 0; s < 8; ++s) {
                    short8 kf = *(const short8*)(kbp + ((t * 8 + s) * 64 + l) * 16);
                    st[0][t] = __builtin_amdgcn_mfma_f32_16x16x32_bf16(kf, qf[0][s], st[0][t], 0, 0, 0);
                    st[1][t] = __builtin_amdgcn_mfma_f32_16x16x32_bf16(kf, qf[1][s], st[1][t], 0, 0, 0);
                }
            const int kl0 = c * 32;
            short8 pf[2];
#pragma unroll
            for (int u = 0; u < 2; ++u) {
                const int lim = 512 + qbw + u * 16 + m;
                const bool needmask = (kl0 + 31) > lim;
                float p[8];
#pragma unroll
                for (int t = 0; t < 2; ++t)
#pragma unroll
                    for (int r = 0; r < 4; ++r) {
                        float v = st[u][t][r] * sscale;
                        if (needmask) {
                            int key = kl0 + t * 16 + qd * 4 + r;
                            v = (key <= lim) ? v : -INFINITY;
                        }
                        p[t * 4 + r] = v;
                    }
                float mx = p[0];
#pragma unroll
                for (int i = 1; i < 8; ++i) mx = fmaxf(mx, p[i]);
                mx = fmaxf(mx, __shfl_xor(mx, 16, 64));
                mx = fmaxf(mx, __shfl_xor(mx, 32, 64));
                const float mnew  = fmaxf(mi[u], mx);
                const float alpha = exp2f(mi[u] - mnew);
                float ps = 0.f;
#pragma unroll
                for (int i = 0; i < 8; ++i) { p[i] = exp2f(p[i] - mnew); ps += p[i]; }
                ps += __shfl_xor(ps, 16, 64);
                ps += __shfl_xor(ps, 32, 64);
                li[u] = li[u] * alpha + ps;
                mi[u] = mnew;
                if (!__all(alpha == 1.0f)) {   // alpha==1 multiply is exact -> safe skip
#pragma unroll
                    for (int t = 0; t < 16; ++t) {
                        o[u][t][0] *= alpha; o[u][t][1] *= alpha;
                        o[u][t][2] *= alpha; o[u][t][3] *= alpha;
                    }
                }
                // pack P^T (bf16) + quad shuffle into B-fragment layout
                int pd0 = packbf(p[0], p[1]);
                int pd1 = packbf(p[2], p[3]);
                int pd2 = packbf(p[4], p[5]);
                int pd3 = packbf(p[6], p[7]);
                int x0 = __builtin_amdgcn_ds_bpermute(a0, pd0);
                int y0 = __builtin_amdgcn_ds_bpermute(a0, pd2);
                int x1 = __builtin_amdgcn_ds_bpermute(a0, pd1);
                int y1 = __builtin_amdgcn_ds_bpermute(a0, pd3);
                int x2 = __builtin_amdgcn_ds_bpermute(a1, pd0);
                int y2 = __builtin_amdgcn_ds_bpermute(a1, pd2);
                int x3 = __builtin_amdgcn_ds_bpermute(a1, pd1);
                int y3 = __builtin_amdgcn_ds_bpermute(a1, pd3);
                PFU pu;
                pu.i[0] = hi ? y0 : x0;
                pu.i[1] = hi ? y1 : x1;
                pu.i[2] = hi ? y2 : x2;
                pu.i[3] = hi ? y3 : x3;
                pf[u] = pu.v;
            }
            // O^T += V^T · P^T, both q-tiles per vf read (2x reuse)
            const char* vbp = vbuf[pb];
#pragma unroll
            for (int t = 0; t < 16; ++t) {
                short8 vf = *(const short8*)(vbp + (t * 64 + l) * 16);
                o[0][t] = __builtin_amdgcn_mfma_f32_16x16x32_bf16(vf, pf[0], o[0][t], 0, 0, 0);
                o[1][t] = __builtin_amdgcn_mfma_f32_16x16x32_bf16(vf, pf[1], o[1][t], 0, 0, 0);
            }
        }
        // ---- stage chunk c+1 (regs -> buf[pb^1]); rg dies here, same iter ----
        if (more) {
            char* dst = (isK ? kbuf[pb ^ 1] : vbuf[pb ^ 1]) + lbase;
#pragma unroll
            for (int i = 0; i < 4; ++i)
                *(int4*)(dst + i * 1024) = rg[i];
        }
        __syncthreads();
        pb ^= 1;
    }

    // ---- epilogue: O/l + residual, write out[b][d][n] (coalesced in n) ----
#pragma unroll
    for (int u = 0; u < 2; ++u) {
        const float inv = 1.f / li[u];
        const int ng = w * WIN + qbw + u * 16 + m;
        const float* xr  = x   + (size_t)b * DIM * NSEQ + ng;
        float*       orw = out + (size_t)b * DIM * NSEQ + ng;
#pragma unroll
        for (int t = 0; t < 16; ++t)
#pragma unroll
            for (int r = 0; r < 4; ++r) {
                int d = t * 16 + qd * 4 + r;
                orw[(size_t)d * NSEQ] = xr[(size_t)d * NSEQ] + o[u][t][r] * inv;
            }
    }
}

// ---------------------------------------------------------------------------
extern "C" void kernel_launch(void* const* d_in, const int* in_sizes, int n_in,
                              void* d_out, int out_size, void* d_ws, size_t ws_size,
                              hipStream_t stream) {
    const float* x  = (const float*)d_in[0];
    const float* Wq = (const float*)d_in[1];
    const float* bq = (const float*)d_in[2];
    const float* Wk = (const float*)d_in[3];
    const float* bk = (const float*)d_in[4];
    const float* Wv = (const float*)d_in[5];
    const float* bv = (const float*)d_in[6];

    char* ws = (char*)d_ws;
    const size_t SZ = (size_t)BATCH * NSEQ * DIM * sizeof(__hip_bfloat16);  // 32 MB
    __hip_bfloat16* xT  = (__hip_bfloat16*)(ws);
    __hip_bfloat16* qb_ = (__hip_bfloat16*)(ws + SZ);
    __hip_bfloat16* kb_ = (__hip_bfloat16*)(ws + 2 * SZ);
    __hip_bfloat16* vt_ = (__hip_bfloat16*)(ws + 3 * SZ);
    __hip_bfloat16* wb_ = (__hip_bfloat16*)(ws + 4 * SZ);                   // 384 KB

    k_transpose<<<dim3(NSEQ / 64, DIM / 64, BATCH), 256, 0, stream>>>(x, xT);
    k_wcast<<<dim3(192), 256, 0, stream>>>(Wq, Wk, Wv, wb_);
    k_proj<<<dim3(128, 3, BATCH), 256, 0, stream>>>(xT, wb_, bq, bk, bv, qb_, kb_, vt_);
    k_attn<<<dim3(16, BATCH, 2), 512, 0, stream>>>(qb_, kb_, vt_, x, (float*)d_out);
}